// Round 16
// baseline (161.455 us; speedup 1.0000x reference)
//
#include <hip/hip_runtime.h>
#include <stdint.h>

#define DMAX 80
#define BLK  256
#define XW   96      // xsel row stride (>= m+1, sentinel 1.0 at k>=m)
#define CW   1024    // column window per block
#define R    4       // rows per block (same alignment class, stride 4)

typedef float f32x4 __attribute__((ext_vector_type(4)));

// ---------------------------------------------------------------------------
// Setup: mask detect + compact idx; coltab of 3-index entries i|j<<8|k<<16
// (column c = xsel[i]*xsel[j]*xsel[k], sentinel index m -> 1.0), plus 3
// shifted copies (copy s at coltab[s*tpad + (c-s)] holds column c) so any
// column phase s = c&3 has a 16B-aligned uint4 load.
// ---------------------------------------------------------------------------
__global__ void maskde_setup(const void* __restrict__ mask_raw, int m,
                             int* __restrict__ idx_out,
                             uint32_t* __restrict__ coltab,
                             int tpad, int T, int P) {
    int tid = blockIdx.x * blockDim.x + threadIdx.x;

    if (tid == 0) {
        const uint8_t* b8  = (const uint8_t*)mask_raw;
        const int*     b32 = (const int*)mask_raw;
        const float*   bf  = (const float*)mask_raw;
        int cnt = 0; bool ok = true;
        for (int i = 0; i < DMAX; ++i) { uint8_t v = b8[i]; if (v > 1) ok = false; cnt += (v != 0); }
        int mode;
        if (ok && cnt == m) {
            mode = 0;
        } else {
            cnt = 0; ok = true;
            for (int i = 0; i < DMAX; ++i) { int v = b32[i]; if (v != 0 && v != 1) ok = false; cnt += (v != 0); }
            mode = (ok && cnt == m) ? 1 : 2;
        }
        int k = 0;
        for (int i = 0; i < DMAX && k < m; ++i) {
            bool on = (mode == 0) ? (b8[i] != 0)
                    : (mode == 1) ? (b32[i] != 0)
                                  : (bf[i] != 0.0f);
            if (on) idx_out[k++] = i;
        }
    }

    int stride = gridDim.x * blockDim.x;
    for (int p = tid; p < P; p += stride) {
        int rem = p, i = 0;
        while (rem >= m - i) { rem -= (m - i); ++i; }
        int j = i + rem;

        #define WR4(c, v) do {                                              \
            int _c = (c); uint32_t _v = (v);                                \
            coltab[_c] = _v;                                                \
            if (_c >= 1) coltab[tpad     + _c - 1] = _v;                    \
            if (_c >= 2) coltab[2 * tpad + _c - 2] = _v;                    \
            if (_c >= 3) coltab[3 * tpad + _c - 3] = _v;                    \
        } while (0)

        uint32_t mm8  = (uint32_t)m << 8;
        uint32_t mm16 = (uint32_t)m << 16;
        if (p < m)
            WR4(p, (uint32_t)p | mm8 | mm16);                       // order-1
        WR4(m + p, (uint32_t)i | ((uint32_t)j << 8) | mm16);        // order-2

        int mi = m - i;
        long long Si  = ((long long)m * (m + 1) * (m + 2)
                       - (long long)mi * (mi + 1) * (mi + 2)) / 6;
        int Rij = ((m - i) + (m - j + 1)) * (j - i) / 2;
        int base = m + P + (int)Si + Rij;
        uint32_t ij = (uint32_t)i | ((uint32_t)j << 8);
        for (int k3 = j; k3 < m; ++k3)
            WR4(base + (k3 - j), ij | ((uint32_t)k3 << 16));
        #undef WR4
    }
}

// ---------------------------------------------------------------------------
// xsel[row*XW + k] = x[row*80 + idx[k]] for k<m, 1.0 for k>=m (sentinel).
// ---------------------------------------------------------------------------
__global__ void maskde_xsel(const float* __restrict__ x,
                            const int* __restrict__ idx,
                            float* __restrict__ xsel, int m, int rows) {
    int g = blockIdx.x * BLK + threadIdx.x;
    int total = rows * XW;
    for (; g < total; g += gridDim.x * BLK) {
        int row = g / XW, k = g - row * XW;
        xsel[g] = (k < m) ? x[row * DMAX + idx[k]] : 1.0f;
    }
}

// ---------------------------------------------------------------------------
// Expand: block = (4 same-class rows: cls+16g+4u) x (1024-col window).
// Same class (row stride 4, T odd) => shared store-alignment phase => ONE
// uint4 table load feeds FOUR aligned float4 stores from registers.
// L2->CU read per 64B written: 16B (ratio 1.25 vs v14's 2.0).
// Prologue: 4x96 xls gather + one barrier (no pps).
// ---------------------------------------------------------------------------
__global__ __launch_bounds__(BLK) void
maskde_expand(const float* __restrict__ xsel,
              const uint32_t* __restrict__ coltab, int tpad,
              float* __restrict__ out, int T, int rows,
              int ncc, int gpc) {
    __shared__ float xls[R][XW];

    const int tid = threadIdx.x;
    const int rg  = blockIdx.x / ncc;
    const int cc  = blockIdx.x - rg * ncc;
    const int cls = rg / gpc;
    const int gix = rg - cls * gpc;

    const int row0 = cls + 16 * gix;       // rows: row0 + 4u, u=0..3
    const int c0   = cc * CW;
    const int cend = (c0 + CW < T) ? c0 + CW : T;

    // prologue: gather 4 rows' selected values
    for (int q = tid; q < R * XW; q += BLK) {
        int u = q / XW, k = q - u * XW;
        int row = row0 + 4 * u;
        xls[u][k] = (row < rows) ? xsel[row * XW + k] : 1.0f;
    }
    __syncthreads();

    // shared alignment phase: (row*T + c0) mod 4 identical for all 4 rows
    const long long rs0 = (long long)row0 * T;
    const int a4 = (int)((rs0 + c0) & 3);
    const int d  = (4 - a4) & 3;           // head elems per row
    int cd = c0 + d;                       // first aligned column
    if (cd > cend) cd = cend;
    const int nq   = (cend - cd) >> 2;     // aligned quads per row
    const int ct   = cd + 4 * nq;          // tail start column
    const int tcnt = cend - ct;            // tail elems per row (<=3)

    const int s = cd & 3;
    const uint4* tb = (const uint4*)(coltab + (size_t)s * tpad + (cd & ~3));

    // per-row output base (at column cd)
    float* ob[R];
    int nr = 0;
#pragma unroll
    for (int u = 0; u < R; ++u) {
        int row = row0 + 4 * u;
        if (row < rows) { ob[u] = out + (size_t)row * T + cd; nr = u + 1; }
        else            { ob[u] = nullptr; }
    }

    // scalar head/tail (<=3 elems per row each, base table copy)
    if (tid < 8) {
        int u = tid >> 1, half = tid & 1;   // 4 rows x {head,tail}
        if (u < nr && ob[u]) {
            if (half == 0) {
                for (int w = 0; w < d; ++w) {
                    uint32_t e = coltab[c0 + w];
                    ob[u][w - d] = xls[u][e & 0xFF] * xls[u][(e >> 8) & 0xFF]
                                 * xls[u][e >> 16];
                }
            } else {
                for (int w = 0; w < tcnt; ++w) {
                    uint32_t e = coltab[ct + w];
                    ob[u][(ct - cd) + w] = xls[u][e & 0xFF]
                                         * xls[u][(e >> 8) & 0xFF]
                                         * xls[u][e >> 16];
                }
            }
        }
    }

    // hot loop: 1 uint4 table load -> 4 aligned float4 stores (registers)
    for (int q = tid; q < nq; q += BLK) {
        uint4 t = tb[q];
#pragma unroll
        for (int u = 0; u < R; ++u) {
            if (ob[u]) {
                const float* xr = xls[u];
                f32x4 o;
                o.x = xr[t.x & 0xFF] * xr[(t.x >> 8) & 0xFF] * xr[t.x >> 16];
                o.y = xr[t.y & 0xFF] * xr[(t.y >> 8) & 0xFF] * xr[t.y >> 16];
                o.z = xr[t.z & 0xFF] * xr[(t.z >> 8) & 0xFF] * xr[t.z >> 16];
                o.w = xr[t.w & 0xFF] * xr[(t.w >> 8) & 0xFF] * xr[t.w >> 16];
                *(f32x4*)(ob[u] + 4 * q) = o;
            }
        }
    }
}

extern "C" void kernel_launch(void* const* d_in, const int* in_sizes, int n_in,
                              void* d_out, int out_size, void* d_ws, size_t ws_size,
                              hipStream_t stream) {
    const float* x    = (const float*)d_in[0];
    const void*  mask = d_in[1];
    float*       out  = (float*)d_out;

    int rows = in_sizes[0] / DMAX;
    if (rows <= 0 || out_size <= 0) return;
    long long Tll = (long long)out_size / rows;

    // recover m from T(m) = m + m(m+1)/2 + m(m+1)(m+2)/6
    int m = -1;
    for (int mm = 0; mm <= DMAX; ++mm) {
        long long t = (long long)mm
                    + (long long)mm * (mm + 1) / 2
                    + (long long)mm * (mm + 1) * (mm + 2) / 6;
        if (t == Tll) { m = mm; break; }
    }
    if (m <= 0) return;

    int T    = (int)Tll;
    int P    = m * (m + 1) / 2;
    int tpad = (T + 3) & ~3;

    // workspace layout (256B-aligned regions)
    char* ws = (char*)d_ws;
    int*      idx    = (int*)ws;                              // 512 B
    uint32_t* coltab = (uint32_t*)(ws + 32768);               // 4*tpad u32
    size_t off_xsel  = 32768 + (size_t)4 * tpad * 4 + 256;
    off_xsel = (off_xsel + 255) & ~(size_t)255;
    float*    xsel   = (float*)(ws + off_xsel);               // rows*XW f32

    int sblocks = (P + 255) / 256;
    if (sblocks < 1) sblocks = 1;
    maskde_setup<<<sblocks, 256, 0, stream>>>(mask, m, idx, coltab,
                                              tpad, T, P);

    int xblocks = (rows * XW + BLK - 1) / BLK;
    if (xblocks > 2048) xblocks = 2048;
    maskde_xsel<<<xblocks, BLK, 0, stream>>>(x, idx, xsel, m, rows);

    int ncc = (T + CW - 1) / CW;            // column chunks
    int rpc = (rows + 3) / 4;               // rows per class (ceil)
    int gpc = (rpc + R - 1) / R;            // row-groups per class
    int nb  = 4 * gpc * ncc;
    maskde_expand<<<nb, BLK, 0, stream>>>(xsel, coltab, tpad, out,
                                          T, rows, ncc, gpc);
}

// Round 17
// 127.385 us; speedup vs baseline: 1.2675x; 1.2675x over previous
//
#include <hip/hip_runtime.h>
#include <stdint.h>

#define DMAX 80
#define BLK  256
#define XW   96      // xsel row stride (>= m+1, sentinel 1.0 at k>=m)
#define EPB  4096    // output elements per block (16 KB), single write stream

typedef float f32x4 __attribute__((ext_vector_type(4)));

// ---------------------------------------------------------------------------
// Setup: mask detect + compact idx; pair16 (i|j<<8); column table with 3
// shifted copies (copy s at tab[s*tpad+(c-s)] holds column c) so any column
// phase s=c&3 has an aligned vector load.  Entry: u16 p|k<<10 when P<1024
// && m<63, else u32 p|k<<16.  column c = pps[p]*xsel[k]:
//   [0,m)      order-1: p=P (sentinel pps=1), k=c
//   [m, m+P)   order-2: p=rank,               k=m (sentinel xsel=1)
//   [m+P, T)   order-3: run over k in [j,m) per pair (i,j)
// ---------------------------------------------------------------------------
__global__ void maskde_setup(const void* __restrict__ mask_raw, int m,
                             int* __restrict__ idx_out,
                             uint16_t* __restrict__ pair16,
                             uint16_t* __restrict__ tab16,
                             uint32_t* __restrict__ tab32,
                             int use16, int tpad, int T, int P) {
    int tid = blockIdx.x * blockDim.x + threadIdx.x;

    if (tid == 0) {
        const uint8_t* b8  = (const uint8_t*)mask_raw;
        const int*     b32 = (const int*)mask_raw;
        const float*   bf  = (const float*)mask_raw;
        int cnt = 0; bool ok = true;
        for (int i = 0; i < DMAX; ++i) { uint8_t v = b8[i]; if (v > 1) ok = false; cnt += (v != 0); }
        int mode;
        if (ok && cnt == m) {
            mode = 0;
        } else {
            cnt = 0; ok = true;
            for (int i = 0; i < DMAX; ++i) { int v = b32[i]; if (v != 0 && v != 1) ok = false; cnt += (v != 0); }
            mode = (ok && cnt == m) ? 1 : 2;
        }
        int k = 0;
        for (int i = 0; i < DMAX && k < m; ++i) {
            bool on = (mode == 0) ? (b8[i] != 0)
                    : (mode == 1) ? (b32[i] != 0)
                                  : (bf[i] != 0.0f);
            if (on) idx_out[k++] = i;
        }
    }

    int stride = gridDim.x * blockDim.x;
    for (int p = tid; p < P; p += stride) {
        int rem = p, i = 0;
        while (rem >= m - i) { rem -= (m - i); ++i; }
        int j = i + rem;

        pair16[p] = (uint16_t)(i | (j << 8));

        #define WR4(c, pf, kf) do {                                          \
            int _c = (c);                                                    \
            if (use16) {                                                     \
                uint16_t _v = (uint16_t)((pf) | ((kf) << 10));               \
                tab16[_c] = _v;                                              \
                if (_c >= 1) tab16[tpad     + _c - 1] = _v;                  \
                if (_c >= 2) tab16[2 * tpad + _c - 2] = _v;                  \
                if (_c >= 3) tab16[3 * tpad + _c - 3] = _v;                  \
            } else {                                                         \
                uint32_t _v = (uint32_t)(pf) | ((uint32_t)(kf) << 16);       \
                tab32[_c] = _v;                                              \
                if (_c >= 1) tab32[tpad     + _c - 1] = _v;                  \
                if (_c >= 2) tab32[2 * tpad + _c - 2] = _v;                  \
                if (_c >= 3) tab32[3 * tpad + _c - 3] = _v;                  \
            }                                                                \
        } while (0)

        if (p < m) WR4(p, P, p);                  // order-1
        WR4(m + p, p, m);                         // order-2

        int mi = m - i;
        long long Si  = ((long long)m * (m + 1) * (m + 2)
                       - (long long)mi * (mi + 1) * (mi + 2)) / 6;
        int Rij = ((m - i) + (m - j + 1)) * (j - i) / 2;
        int base = m + P + (int)Si + Rij;
        for (int k3 = j; k3 < m; ++k3)
            WR4(base + (k3 - j), p, k3);
        #undef WR4
    }
}

// ---------------------------------------------------------------------------
// xsel[row*XW + k] = x[row*80 + idx[k]] for k<m, 1.0 for k>=m (sentinel).
// ---------------------------------------------------------------------------
__global__ void maskde_xsel(const float* __restrict__ x,
                            const int* __restrict__ idx,
                            float* __restrict__ xsel, int m, int rows) {
    int g = blockIdx.x * BLK + threadIdx.x;
    int total = rows * XW;
    for (; g < total; g += gridDim.x * BLK) {
        int row = g / XW, k = g - row * XW;
        xsel[g] = (k < m) ? x[row * DMAX + idx[k]] : 1.0f;
    }
}

// ---------------------------------------------------------------------------
// Expand (v14 write structure + pps + u16 table): block b writes flat
// [b*EPB,(b+1)*EPB), single contiguous stream.  Prologue: xls gather (lazy
// row 1) + pps build (P+1 per row).  Hot loop: one 8B-aligned uint2 table
// load (u16 path; halves L2 read traffic) + 8 LDS reads + 4 muls + one
// aligned float4 store, 4 iterations per thread.
// ---------------------------------------------------------------------------
template<bool U16>
__global__ __launch_bounds__(BLK) void
maskde_expand(const float* __restrict__ xsel,
              const uint16_t* __restrict__ pair16,
              const uint16_t* __restrict__ tab16,
              const uint32_t* __restrict__ tab32,
              int tpad, float* __restrict__ out,
              int T, int P, int rows, int total) {
    extern __shared__ float sm[];
    float* xls0 = sm;            // XW
    float* xls1 = sm + XW;       // XW
    float* pps0 = sm + 2 * XW;   // P+1
    float* pps1 = pps0 + (P + 1);

    const int tid  = threadIdx.x;
    const int e0   = blockIdx.x * EPB;
    if (e0 >= total) return;
    const int eend = (e0 + EPB < total) ? e0 + EPB : total;
    const int r0   = e0 / T;
    const int r0start = r0 * T;
    const bool need1 = ((eend - 1) / T) > r0;   // span crosses into row r0+1

    // gather selected values (waves 0-1: row0, waves 2-3: row1 if needed)
    if (tid < XW) {
        xls0[tid] = xsel[r0 * XW + tid];
    } else if (tid >= 128 && tid < 128 + XW) {
        int k = tid - 128;
        xls1[k] = need1 ? xsel[(r0 + 1) * XW + k] : 1.0f;
    }
    __syncthreads();

    // pair products (+ sentinel at P); second row only if needed
    for (int p = tid; p <= P; p += BLK) {
        float v0 = 1.0f, v1 = 1.0f;
        if (p < P) {
            uint32_t ij = pair16[p];
            int i = ij & 0xFF, j = (ij >> 8) & 0xFF;
            v0 = xls0[i] * xls0[j];
            if (need1) v1 = xls1[i] * xls1[j];
        }
        pps0[p] = v0;
        if (need1) pps1[p] = v1;
    }
    __syncthreads();

#pragma unroll
    for (int it = 0; it < EPB / (4 * BLK); ++it) {
        int ee = e0 + (tid << 2) + it * (4 * BLK);
        if (ee >= total) break;
        int c = ee - r0start;
        const float* pS = pps0;
        const float* xS = xls0;
        if (c >= T) { c -= T; pS = pps1; xS = xls1; }

        if (c <= T - 4 && ee + 3 < total) {
            int s = c & 3;
            f32x4 o;
            if constexpr (U16) {
                uint2 t = *(const uint2*)(tab16 + (size_t)s * tpad + (c - s));
                o.x = pS[t.x & 0x3FF]         * xS[(t.x >> 10) & 0x3F];
                o.y = pS[(t.x >> 16) & 0x3FF] * xS[t.x >> 26];
                o.z = pS[t.y & 0x3FF]         * xS[(t.y >> 10) & 0x3F];
                o.w = pS[(t.y >> 16) & 0x3FF] * xS[t.y >> 26];
            } else {
                uint4 t = *(const uint4*)(tab32 + (size_t)s * tpad + (c - s));
                o.x = pS[t.x & 0xFFFF] * xS[t.x >> 16];
                o.y = pS[t.y & 0xFFFF] * xS[t.y >> 16];
                o.z = pS[t.z & 0xFFFF] * xS[t.z >> 16];
                o.w = pS[t.w & 0xFFFF] * xS[t.w >> 16];
            }
            *(f32x4*)(out + ee) = o;   // ee % 4 == 0 -> 16B aligned
        } else {
            // row-crossing quad or buffer tail: scalar (base table copy)
            for (int u = 0; u < 4; ++u) {
                int e2 = ee + u;
                if (e2 >= total) break;
                int c2 = e2 - r0start;
                const float* p2 = pps0;
                const float* x2 = xls0;
                if (c2 >= T) { c2 -= T; p2 = pps1; x2 = xls1; }
                uint32_t p_, k_;
                if constexpr (U16) { uint16_t t = tab16[c2]; p_ = t & 0x3FF; k_ = t >> 10; }
                else               { uint32_t t = tab32[c2]; p_ = t & 0xFFFF; k_ = t >> 16; }
                out[e2] = p2[p_] * x2[k_];
            }
        }
    }
}

extern "C" void kernel_launch(void* const* d_in, const int* in_sizes, int n_in,
                              void* d_out, int out_size, void* d_ws, size_t ws_size,
                              hipStream_t stream) {
    const float* x    = (const float*)d_in[0];
    const void*  mask = d_in[1];
    float*       out  = (float*)d_out;

    int rows = in_sizes[0] / DMAX;
    if (rows <= 0 || out_size <= 0) return;
    long long Tll = (long long)out_size / rows;

    // recover m from T(m) = m + m(m+1)/2 + m(m+1)(m+2)/6
    int m = -1;
    for (int mm = 0; mm <= DMAX; ++mm) {
        long long t = (long long)mm
                    + (long long)mm * (mm + 1) / 2
                    + (long long)mm * (mm + 1) * (mm + 2) / 6;
        if (t == Tll) { m = mm; break; }
    }
    if (m <= 0) return;

    int T     = (int)Tll;
    int P     = m * (m + 1) / 2;
    int tpad  = (T + 3) & ~3;
    int total = rows * T;
    int use16 = (P < 1024 && m < 63) ? 1 : 0;

    // workspace layout (256B-aligned regions)
    char* ws = (char*)d_ws;
    int*      idx    = (int*)ws;                              // 512 B
    uint16_t* pair16 = (uint16_t*)(ws + 1024);                // 2P B
    uint16_t* tab16  = (uint16_t*)(ws + 32768);               // 4*tpad u16
    uint32_t* tab32  = (uint32_t*)(ws + 32768);               // 4*tpad u32 (aliased)
    size_t off_xsel  = 32768 + (size_t)4 * tpad * 4 + 256;
    off_xsel = (off_xsel + 255) & ~(size_t)255;
    float*    xsel   = (float*)(ws + off_xsel);               // rows*XW f32

    int sblocks = (P + 255) / 256;
    if (sblocks < 1) sblocks = 1;
    maskde_setup<<<sblocks, 256, 0, stream>>>(mask, m, idx, pair16, tab16,
                                              tab32, use16, tpad, T, P);

    int xblocks = (rows * XW + BLK - 1) / BLK;
    if (xblocks > 2048) xblocks = 2048;
    maskde_xsel<<<xblocks, BLK, 0, stream>>>(x, idx, xsel, m, rows);

    int nb = (total + EPB - 1) / EPB;
    size_t shmem = (size_t)(2 * XW + 2 * (P + 1)) * sizeof(float);
    if (use16)
        maskde_expand<true><<<nb, BLK, shmem, stream>>>(xsel, pair16, tab16,
                                                        tab32, tpad, out,
                                                        T, P, rows, total);
    else
        maskde_expand<false><<<nb, BLK, shmem, stream>>>(xsel, pair16, tab16,
                                                         tab32, tpad, out,
                                                         T, P, rows, total);
}